// Round 1
// 158.523 us; speedup vs baseline: 1.0472x; 1.0472x over previous
//
#include <hip/hip_runtime.h>

#define B_SZ 1024
#define DIN 512
#define HH 512   // H
#define DOUT 512

typedef short bf16x8 __attribute__((ext_vector_type(8)));
typedef float f32x4 __attribute__((ext_vector_type(4)));

__device__ __forceinline__ unsigned short f2bf(float f) {
    unsigned int u = __float_as_uint(f);
    u += 0x7FFFu + ((u >> 16) & 1u);          // RTNE
    return (unsigned short)(u >> 16);
}
__device__ __forceinline__ float bf2f(unsigned short s) {
    return __uint_as_float(((unsigned int)s) << 16);
}

// ---------------------------------------------------------------------------
// Fragment-linear bf16 hi/lo split layouts for MFMA 16x16x32.
// A-side (x or h, [1024][512] fp32) -> Afr[48 ks][64 mf][64 lanes]{uint4}:
//   element (lane,j) = Asplit[mf*16 + (lane&15)][k'], k' = ks*32 + (lane>>4)*8 + j
//   Asplit over k' in [0,512)=hi, [512,1024)=lo, [1024,1536)=hi   (terms hi,lo,hi)
// B-side (W, [512][512] fp32 k-major) -> Bfr[48 ks][32 nf][64 lanes]{uint4}:
//   element (lane,j) = Wsplit[k'][nf*16 + (lane&15)]
//   Wsplit terms: hi, hi, lo   => sum = AhiWhi + AloWhi + AhiWlo  (~fp32 accurate)
// Only the lane&15 = row/col mapping + the m89-verified C/D layout matter; the
// k'<->j map is the same bijection on both operands, so MFMA sums it correctly.
// ---------------------------------------------------------------------------
__device__ __forceinline__ void conv_split_body(const float* __restrict__ src,
                                                uint4* __restrict__ dst, int t) {
    const int lane = t & 63;
    const int fb   = t >> 6;         // ks*64 + mf
    const int ks   = fb >> 6;
    const int mf   = fb & 63;
    const int row  = mf * 16 + (lane & 15);
    const int kb   = ks * 32 + ((lane >> 4) << 3);
    const int term = kb >> 9;        // 0,1,2 -> hi,lo,hi (uniform per thread: kb%8==0)
    const int c    = kb & 511;
    const float4 a0 = *(const float4*)&src[(size_t)row * 512 + c];
    const float4 a1 = *(const float4*)&src[(size_t)row * 512 + c + 4];
    const float av[8] = {a0.x, a0.y, a0.z, a0.w, a1.x, a1.y, a1.z, a1.w};
    unsigned short o[8];
    #pragma unroll
    for (int j = 0; j < 8; ++j) {
        unsigned short hi = f2bf(av[j]);
        o[j] = (term == 1) ? f2bf(av[j] - bf2f(hi)) : hi;
    }
    uint4 v;
    v.x = (unsigned int)o[0] | ((unsigned int)o[1] << 16);
    v.y = (unsigned int)o[2] | ((unsigned int)o[3] << 16);
    v.z = (unsigned int)o[4] | ((unsigned int)o[5] << 16);
    v.w = (unsigned int)o[6] | ((unsigned int)o[7] << 16);
    dst[t] = v;
}

__device__ __forceinline__ void convW_body(const float* __restrict__ W,
                                           uint4* __restrict__ dst, int t) {
    const int lane = t & 63;
    const int fb   = t >> 6;         // ks*32 + nf
    const int ks   = fb >> 5;
    const int nf   = fb & 31;
    const int col  = nf * 16 + (lane & 15);
    const int kb   = ks * 32 + ((lane >> 4) << 3);
    const int term = kb >> 9;        // 0,1,2 -> hi,hi,lo
    const int c0   = kb & 511;
    unsigned short o[8];
    #pragma unroll
    for (int j = 0; j < 8; ++j) {
        const float f = W[(size_t)(c0 + j) * 512 + col];
        unsigned short hi = f2bf(f);
        o[j] = (term == 2) ? f2bf(f - bf2f(hi)) : hi;
    }
    uint4 v;
    v.x = (unsigned int)o[0] | ((unsigned int)o[1] << 16);
    v.y = (unsigned int)o[2] | ((unsigned int)o[3] << 16);
    v.z = (unsigned int)o[4] | ((unsigned int)o[5] << 16);
    v.w = (unsigned int)o[6] | ((unsigned int)o[7] << 16);
    dst[t] = v;
}

// ---------------------------------------------------------------------------
// prep_all: fused (block-range dispatch)
//   [0,1022)     wb[i][j] = (j>i) ? {W_hh,b_hh} : {0,-1}   (scan weights)
//   [1022,1790)  x  -> Afr  (768 blocks, 196608 threads)
//   [1790,2174)  W_in  -> Bin  (384 blocks)
//   [2174,2558)  W_out -> Bout (384 blocks)
// ---------------------------------------------------------------------------
__global__ __launch_bounds__(256)
void prep_all(const float* __restrict__ W_hh, const float* __restrict__ b_hh,
              float2* __restrict__ wb,
              const float* __restrict__ x, uint4* __restrict__ Afr,
              const float* __restrict__ W_in, uint4* __restrict__ Bin,
              const float* __restrict__ W_out, uint4* __restrict__ Bout) {
    const int b = blockIdx.x;
    const int tid = threadIdx.x;
    if (b < 1022) {
        const int idx = b * 256 + tid;       // over (H-1)*H
        const int i = idx >> 9;
        const int j = idx & 511;
        float2 o;
        if (j > i) { o.x = W_hh[idx]; o.y = b_hh[idx]; }
        else       { o.x = 0.0f;      o.y = -1.0f;     }
        wb[idx] = o;
    } else if (b < 1790) {
        conv_split_body(x, Afr, (b - 1022) * 256 + tid);
    } else if (b < 2174) {
        convW_body(W_in, Bin, (b - 1790) * 256 + tid);
    } else {
        convW_body(W_out, Bout, (b - 2174) * 256 + tid);
    }
}

__global__ __launch_bounds__(256)
void conv_h(const float* __restrict__ h, uint4* __restrict__ Afr) {
    conv_split_body(h, Afr, blockIdx.x * 256 + threadIdx.x);
}

// ---------------------------------------------------------------------------
// MFMA GEMM: C[1024,512] = act(A @ W + bias), A/W pre-split to bf16 hi/lo,
// K' = 1536 packed. Tile 64x32, grid 16x16 = 256 blocks (1/CU), 4 waves.
// Wave w: rows (w&1)*32..+32 (2 mf), cols (w>>1)*16 (1 nf). BK=64 (2 ks).
// LDS double-buffered 2x12KB, register-relay prefetch, 1 barrier/iter.
// ---------------------------------------------------------------------------
template <bool ACT>
__global__ __launch_bounds__(256)
void mfma_gemm(const uint4* __restrict__ Ag,   // [48][64][64] uint4
               const uint4* __restrict__ Bg,   // [48][32][64] uint4
               const float* __restrict__ bias,
               float* __restrict__ C) {
    __shared__ uint4 lds[2][768];              // per buf: A 512 (2ks x 4mf x 64), B 256
    const int tid  = threadIdx.x;
    const int lane = tid & 63;
    const int w    = tid >> 6;
    const int wr   = w & 1;
    const int wc   = w >> 1;
    const int mf0  = blockIdx.x * 4;
    const int nf0  = blockIdx.y * 2;

    const int a_mfs = (tid >> 6) & 3;          // staging: A mf slot
    const int b_ks  = tid >> 7;                // staging: B ks slot
    const int b_nfs = (tid >> 6) & 1;          // staging: B nf slot

    uint4 R0, R1, R2;
    auto stage = [&](int s) {
        const int ks0 = s * 2;
        R0 = Ag[(size_t)((ks0    ) * 64 + mf0 + a_mfs) * 64 + lane];
        R1 = Ag[(size_t)((ks0 + 1) * 64 + mf0 + a_mfs) * 64 + lane];
        R2 = Bg[(size_t)((ks0 + b_ks) * 32 + nf0 + b_nfs) * 64 + lane];
    };

    f32x4 acc0 = {0.f, 0.f, 0.f, 0.f};
    f32x4 acc1 = {0.f, 0.f, 0.f, 0.f};

    stage(0);
    lds[0][tid] = R0; lds[0][256 + tid] = R1; lds[0][512 + tid] = R2;
    stage(1);
    __syncthreads();

    for (int s = 0; s < 24; ++s) {
        const int cur = s & 1;
        if (s + 1 < 24) {                      // write next buf from relay regs
            const int nxt = cur ^ 1;
            lds[nxt][tid] = R0; lds[nxt][256 + tid] = R1; lds[nxt][512 + tid] = R2;
        }
        if (s + 2 < 24) stage(s + 2);          // prefetch tile s+2 into regs
        __builtin_amdgcn_sched_barrier(0);     // pin loads/writes above compute

        bf16x8 aF[2][2], bF[2];
        #pragma unroll
        for (int ksL = 0; ksL < 2; ++ksL) {
            #pragma unroll
            for (int mfL = 0; mfL < 2; ++mfL)
                aF[ksL][mfL] = *(const bf16x8*)&lds[cur][ksL * 256 + (wr * 2 + mfL) * 64 + lane];
            bF[ksL] = *(const bf16x8*)&lds[cur][512 + (ksL * 2 + wc) * 64 + lane];
        }
        #pragma unroll
        for (int ksL = 0; ksL < 2; ++ksL) {
            acc0 = __builtin_amdgcn_mfma_f32_16x16x32_bf16(aF[ksL][0], bF[ksL], acc0, 0, 0, 0);
            acc1 = __builtin_amdgcn_mfma_f32_16x16x32_bf16(aF[ksL][1], bF[ksL], acc1, 0, 0, 0);
        }
        __syncthreads();
    }

    // epilogue: C/D layout (m89-verified): col = lane&15, row = (lane>>4)*4 + r
    const int colg   = (nf0 + wc) * 16 + (lane & 15);
    const float bv   = bias[colg];
    const int rbase0 = (mf0 + wr * 2) * 16 + ((lane >> 4) << 2);
    #pragma unroll
    for (int r = 0; r < 4; ++r) {
        float v = acc0[r] + bv;
        if (ACT) { v = fmaxf(v, 0.f); v = v * v; }
        C[(size_t)(rbase0 + r) * 512 + colg] = v;
    }
    #pragma unroll
    for (int r = 0; r < 4; ++r) {
        float v = acc1[r] + bv;
        if (ACT) { v = fmaxf(v, 0.f); v = v * v; }
        C[(size_t)(rbase0 + 16 + r) * 512 + colg] = v;
    }
}

// ---------------------------------------------------------------------------
// Sequential triangular scan (UNCHANGED this round; next optimization target).
// ---------------------------------------------------------------------------
template <int C>
__device__ __forceinline__ void scan_chunk(const float2* __restrict__ wb,
                                           float2* __restrict__ smem,
                                           float hr[8], int lane) {
    constexpr int W2 = 64 * (8 - C);                         // active cols
    constexpr int T  = (C < 4) ? 8 : (C < 6 ? 16 : (C == 6 ? 32 : 64));
    constexpr int NTILES = 64 / T;
    constexpr int NLD = (T * W2) / 256;                      // relay elems
    const int tid = threadIdx.x;

    float2 R[16];

    auto stage = [&](int i0) {
        #pragma unroll
        for (int q = 0; q < NLD; ++q) {
            const int e = tid + 256 * q;
            const int r = e / W2;              // const divide -> magic mul
            const int col = e - r * W2;
            int row = i0 + r;
            if (row > 510) row = 510;          // only chunk 7's pad row
            R[q] = wb[(size_t)row * HH + 64 * C + col];
        }
    };

    stage(64 * C);                             // preload tile 0
    for (int t = 0; t < NTILES; ++t) {
        __syncthreads();                       // LDS free (prev compute done)
        #pragma unroll
        for (int q = 0; q < NLD; ++q) smem[tid + 256 * q] = R[q];
        __syncthreads();                       // LDS tile ready
        if (t + 1 < NTILES) stage(64 * C + (t + 1) * T);
        __builtin_amdgcn_sched_barrier(0);     // pin prefetch above compute

        #pragma unroll 4
        for (int r = 0; r < T; ++r) {
            const int ii = t * T + r;          // step within chunk (uniform)
            if (C == 7 && ii == 63) break;     // no step 511
            const float hi = __uint_as_float(
                __builtin_amdgcn_readlane(__float_as_uint(hr[C]), ii));
            #pragma unroll
            for (int k = C; k < 8; ++k) {
                const float2 wv = smem[r * W2 + lane + 64 * (k - C)];
                const float tv = fmaf(hi, wv.x, wv.y);
                const float rv = fmaxf(tv, 0.f);
                hr[k] = fmaf(rv, rv, hr[k]);
            }
        }
    }
}

__global__ __launch_bounds__(256)
void scan_kernel(const float2* __restrict__ wb, float* __restrict__ h) {
    __shared__ float2 smem[4096];              // 32 KB, reused per tile
    const int lane = threadIdx.x & 63;
    const int wave = threadIdx.x >> 6;
    const int row  = blockIdx.x * 4 + wave;    // 256 blocks x 4 waves
    float* hrow = h + (size_t)row * HH;

    float hr[8];
    #pragma unroll
    for (int k = 0; k < 8; ++k) hr[k] = hrow[lane + 64 * k];

    scan_chunk<0>(wb, smem, hr, lane);
    scan_chunk<1>(wb, smem, hr, lane);
    scan_chunk<2>(wb, smem, hr, lane);
    scan_chunk<3>(wb, smem, hr, lane);
    scan_chunk<4>(wb, smem, hr, lane);
    scan_chunk<5>(wb, smem, hr, lane);
    scan_chunk<6>(wb, smem, hr, lane);
    scan_chunk<7>(wb, smem, hr, lane);

    #pragma unroll
    for (int k = 0; k < 8; ++k) hrow[lane + 64 * k] = hr[k];
}

// ---------------------------------------------------------------------------
// workspace layout (10 MB total):
//   [0x000000, 0x200000) wb   (511*512 float2)
//   [0x200000, 0x400000) h    (1024*512 fp32)
//   [0x400000, 0x700000) Afr  (48*64*64 uint4 = 3 MB; reused for x then h)
//   [0x700000, 0x880000) Bin  (48*32*64 uint4 = 1.5 MB)
//   [0x880000, 0xA00000) Bout (1.5 MB)
// ---------------------------------------------------------------------------
extern "C" void kernel_launch(void* const* d_in, const int* in_sizes, int n_in,
                              void* d_out, int out_size, void* d_ws, size_t ws_size,
                              hipStream_t stream) {
    const float* x     = (const float*)d_in[0];
    const float* W_in  = (const float*)d_in[1];
    const float* b_in  = (const float*)d_in[2];
    const float* W_hh  = (const float*)d_in[3];
    const float* b_hh  = (const float*)d_in[4];
    const float* W_out = (const float*)d_in[5];
    const float* b_out = (const float*)d_in[6];
    float* out = (float*)d_out;

    char* ws = (char*)d_ws;
    float2* wb  = (float2*)ws;
    float*  h   = (float*)(ws + 0x200000u);
    uint4*  Afr = (uint4*)(ws + 0x400000u);
    uint4*  Bin = (uint4*)(ws + 0x700000u);
    uint4*  Bout= (uint4*)(ws + 0x880000u);

    // 1) fused prep: wb mask-interleave + x/W_in/W_out bf16 hi/lo frag-linear split
    prep_all<<<dim3(2558), dim3(256), 0, stream>>>(W_hh, b_hh, wb,
                                                   x, Afr, W_in, Bin, W_out, Bout);

    // 2) h0 = relu^2(x @ W_in + b_in)  via bf16-split MFMA
    mfma_gemm<true><<<dim3(16, 16), dim3(256), 0, stream>>>(Afr, Bin, b_in, h);

    // 3) sequential triangular scan, in-place on h
    scan_kernel<<<dim3(256), dim3(256), 0, stream>>>(wb, h);

    // 4) split post-scan h into frag-linear bf16 hi/lo
    conv_h<<<dim3(768), dim3(256), 0, stream>>>(h, Afr);

    // 5) out = h @ W_out + b_out
    mfma_gemm<false><<<dim3(16, 16), dim3(256), 0, stream>>>(Afr, Bout, b_out, out);
}

// Round 2
// 157.430 us; speedup vs baseline: 1.0544x; 1.0069x over previous
//
#include <hip/hip_runtime.h>

#define B_SZ 1024
#define DIN 512
#define HH 512   // H
#define DOUT 512

typedef short bf16x8 __attribute__((ext_vector_type(8)));
typedef float f32x4 __attribute__((ext_vector_type(4)));

__device__ __forceinline__ unsigned short f2bf(float f) {
    unsigned int u = __float_as_uint(f);
    u += 0x7FFFu + ((u >> 16) & 1u);          // RTNE
    return (unsigned short)(u >> 16);
}
__device__ __forceinline__ float bf2f(unsigned short s) {
    return __uint_as_float(((unsigned int)s) << 16);
}

// ---------------------------------------------------------------------------
// Fragment-linear bf16 hi/lo split layouts for MFMA 16x16x32.
// A-side (x or h, [1024][512] fp32) -> Afr[48 ks][64 mf][64 lanes]{uint4}:
//   element (lane,j) = Asplit[mf*16 + (lane&15)][k'], k' = ks*32 + (lane>>4)*8 + j
//   Asplit over k' in [0,512)=hi, [512,1024)=lo, [1024,1536)=hi   (terms hi,lo,hi)
// B-side (W, [512][512] fp32 k-major) -> Bfr[48 ks][32 nf][64 lanes]{uint4}:
//   element (lane,j) = Wsplit[k'][nf*16 + (lane&15)]
//   Wsplit terms: hi, hi, lo   => sum = AhiWhi + AloWhi + AhiWlo  (~fp32 accurate)
// Only the lane&15 = row/col mapping + the m89-verified C/D layout matter; the
// k'<->j map is the same bijection on both operands, so MFMA sums it correctly.
// ---------------------------------------------------------------------------
__device__ __forceinline__ void conv_split_body(const float* __restrict__ src,
                                                uint4* __restrict__ dst, int t) {
    const int lane = t & 63;
    const int fb   = t >> 6;         // ks*64 + mf
    const int ks   = fb >> 6;
    const int mf   = fb & 63;
    const int row  = mf * 16 + (lane & 15);
    const int kb   = ks * 32 + ((lane >> 4) << 3);
    const int term = kb >> 9;        // 0,1,2 -> hi,lo,hi (uniform per thread: kb%8==0)
    const int c    = kb & 511;
    const float4 a0 = *(const float4*)&src[(size_t)row * 512 + c];
    const float4 a1 = *(const float4*)&src[(size_t)row * 512 + c + 4];
    const float av[8] = {a0.x, a0.y, a0.z, a0.w, a1.x, a1.y, a1.z, a1.w};
    unsigned short o[8];
    #pragma unroll
    for (int j = 0; j < 8; ++j) {
        unsigned short hi = f2bf(av[j]);
        o[j] = (term == 1) ? f2bf(av[j] - bf2f(hi)) : hi;
    }
    uint4 v;
    v.x = (unsigned int)o[0] | ((unsigned int)o[1] << 16);
    v.y = (unsigned int)o[2] | ((unsigned int)o[3] << 16);
    v.z = (unsigned int)o[4] | ((unsigned int)o[5] << 16);
    v.w = (unsigned int)o[6] | ((unsigned int)o[7] << 16);
    dst[t] = v;
}

__device__ __forceinline__ void convW_body(const float* __restrict__ W,
                                           uint4* __restrict__ dst, int t) {
    const int lane = t & 63;
    const int fb   = t >> 6;         // ks*32 + nf
    const int ks   = fb >> 5;
    const int nf   = fb & 31;
    const int col  = nf * 16 + (lane & 15);
    const int kb   = ks * 32 + ((lane >> 4) << 3);
    const int term = kb >> 9;        // 0,1,2 -> hi,hi,lo
    const int c0   = kb & 511;
    unsigned short o[8];
    #pragma unroll
    for (int j = 0; j < 8; ++j) {
        const float f = W[(size_t)(c0 + j) * 512 + col];
        unsigned short hi = f2bf(f);
        o[j] = (term == 2) ? f2bf(f - bf2f(hi)) : hi;
    }
    uint4 v;
    v.x = (unsigned int)o[0] | ((unsigned int)o[1] << 16);
    v.y = (unsigned int)o[2] | ((unsigned int)o[3] << 16);
    v.z = (unsigned int)o[4] | ((unsigned int)o[5] << 16);
    v.w = (unsigned int)o[6] | ((unsigned int)o[7] << 16);
    dst[t] = v;
}

// ---------------------------------------------------------------------------
// prep_all: fused (block-range dispatch)
//   [0,1022)     wb[i][j] = (j>i) ? {W_hh,b_hh} : {0,-1}   (scan weights)
//   [1022,1790)  x  -> Afr  (768 blocks)
//   [1790,2174)  W_in  -> Bin  (384 blocks)
//   [2174,2558)  W_out -> Bout (384 blocks)
// ---------------------------------------------------------------------------
__global__ __launch_bounds__(256)
void prep_all(const float* __restrict__ W_hh, const float* __restrict__ b_hh,
              float2* __restrict__ wb,
              const float* __restrict__ x, uint4* __restrict__ Afr,
              const float* __restrict__ W_in, uint4* __restrict__ Bin,
              const float* __restrict__ W_out, uint4* __restrict__ Bout) {
    const int b = blockIdx.x;
    const int tid = threadIdx.x;
    if (b < 1022) {
        const int idx = b * 256 + tid;       // over (H-1)*H
        const int i = idx >> 9;
        const int j = idx & 511;
        float2 o;
        if (j > i) { o.x = W_hh[idx]; o.y = b_hh[idx]; }
        else       { o.x = 0.0f;      o.y = -1.0f;     }
        wb[idx] = o;
    } else if (b < 1790) {
        conv_split_body(x, Afr, (b - 1022) * 256 + tid);
    } else if (b < 2174) {
        convW_body(W_in, Bin, (b - 1790) * 256 + tid);
    } else {
        convW_body(W_out, Bout, (b - 2174) * 256 + tid);
    }
}

__global__ __launch_bounds__(256)
void conv_h(const float* __restrict__ h, uint4* __restrict__ Afr) {
    conv_split_body(h, Afr, blockIdx.x * 256 + threadIdx.x);
}

// ---------------------------------------------------------------------------
// MFMA GEMM: C[1024,512] = act(A @ W + bias), A/W pre-split to bf16 hi/lo,
// K' = 1536 packed. Tile 64x32, grid 16x16 = 256 blocks (1/CU), 4 waves.
// (unchanged this round)
// ---------------------------------------------------------------------------
template <bool ACT>
__global__ __launch_bounds__(256)
void mfma_gemm(const uint4* __restrict__ Ag,   // [48][64][64] uint4
               const uint4* __restrict__ Bg,   // [48][32][64] uint4
               const float* __restrict__ bias,
               float* __restrict__ C) {
    __shared__ uint4 lds[2][768];              // per buf: A 512, B 256
    const int tid  = threadIdx.x;
    const int lane = tid & 63;
    const int w    = tid >> 6;
    const int wr   = w & 1;
    const int wc   = w >> 1;
    const int mf0  = blockIdx.x * 4;
    const int nf0  = blockIdx.y * 2;

    const int a_mfs = (tid >> 6) & 3;          // staging: A mf slot
    const int b_ks  = tid >> 7;                // staging: B ks slot
    const int b_nfs = (tid >> 6) & 1;          // staging: B nf slot

    uint4 R0, R1, R2;
    auto stage = [&](int s) {
        const int ks0 = s * 2;
        R0 = Ag[(size_t)((ks0    ) * 64 + mf0 + a_mfs) * 64 + lane];
        R1 = Ag[(size_t)((ks0 + 1) * 64 + mf0 + a_mfs) * 64 + lane];
        R2 = Bg[(size_t)((ks0 + b_ks) * 32 + nf0 + b_nfs) * 64 + lane];
    };

    f32x4 acc0 = {0.f, 0.f, 0.f, 0.f};
    f32x4 acc1 = {0.f, 0.f, 0.f, 0.f};

    stage(0);
    lds[0][tid] = R0; lds[0][256 + tid] = R1; lds[0][512 + tid] = R2;
    stage(1);
    __syncthreads();

    for (int s = 0; s < 24; ++s) {
        const int cur = s & 1;
        if (s + 1 < 24) {                      // write next buf from relay regs
            const int nxt = cur ^ 1;
            lds[nxt][tid] = R0; lds[nxt][256 + tid] = R1; lds[nxt][512 + tid] = R2;
        }
        if (s + 2 < 24) stage(s + 2);          // prefetch tile s+2 into regs
        __builtin_amdgcn_sched_barrier(0);     // pin loads/writes above compute

        bf16x8 aF[2][2], bF[2];
        #pragma unroll
        for (int ksL = 0; ksL < 2; ++ksL) {
            #pragma unroll
            for (int mfL = 0; mfL < 2; ++mfL)
                aF[ksL][mfL] = *(const bf16x8*)&lds[cur][ksL * 256 + (wr * 2 + mfL) * 64 + lane];
            bF[ksL] = *(const bf16x8*)&lds[cur][512 + (ksL * 2 + wc) * 64 + lane];
        }
        #pragma unroll
        for (int ksL = 0; ksL < 2; ++ksL) {
            acc0 = __builtin_amdgcn_mfma_f32_16x16x32_bf16(aF[ksL][0], bF[ksL], acc0, 0, 0, 0);
            acc1 = __builtin_amdgcn_mfma_f32_16x16x32_bf16(aF[ksL][1], bF[ksL], acc1, 0, 0, 0);
        }
        __syncthreads();
    }

    // epilogue: C/D layout (m89-verified): col = lane&15, row = (lane>>4)*4 + r
    const int colg   = (nf0 + wc) * 16 + (lane & 15);
    const float bv   = bias[colg];
    const int rbase0 = (mf0 + wr * 2) * 16 + ((lane >> 4) << 2);
    #pragma unroll
    for (int r = 0; r < 4; ++r) {
        float v = acc0[r] + bv;
        if (ACT) { v = fmaxf(v, 0.f); v = v * v; }
        C[(size_t)(rbase0 + r) * 512 + colg] = v;
    }
    #pragma unroll
    for (int r = 0; r < 4; ++r) {
        float v = acc1[r] + bv;
        if (ACT) { v = fmaxf(v, 0.f); v = v * v; }
        C[(size_t)(rbase0 + 16 + r) * 512 + colg] = v;
    }
}

// ---------------------------------------------------------------------------
// Sequential triangular scan, v3: NO LDS, NO barriers.
// 256 blocks x 4 independent waves; wave w = batch row blockIdx*4+w; lane l
// owns cols l+64k. Weights stream straight from global (L2-resident 2MB,
// identical stream for every wave -> L1 broadcast across the 4 co-resident
// waves) into a PF-deep static register window, software-pipelined.
// Per (step,k) the wave's 64 lanes read 512B contiguous -> one coalesced
// global_load_dwordx2 with SGPR base + imm offset. All slot indices static
// via full unroll of the PF-group (rule #20). FMA order identical to v2 ->
// bitwise-same scan output.
// ---------------------------------------------------------------------------
template <int C>
__device__ __forceinline__ void scan_chunk(const float2* __restrict__ wb,
                                           float hr[8], int lane) {
    constexpr int NK = 8 - C;                          // active col-groups
    constexpr int PF = (C < 4) ? 4 : (C < 6) ? 8 : 16; // pipeline depth
    constexpr int NT = 64 / PF;
    // step s (row i = 64C+s), col-group k: addr = wb[i*512 + 64*(C+k) + lane]
    const float2* base = wb + (size_t)(64 * C) * HH + 64 * C + lane;

    float2 Wb[PF][NK];                                 // static-indexed window
    #pragma unroll
    for (int q = 0; q < PF; ++q)
        #pragma unroll
        for (int k = 0; k < NK; ++k)
            Wb[q][k] = base[(size_t)q * HH + 64 * k];

    for (int t = 0; t < NT; ++t) {
        #pragma unroll
        for (int q = 0; q < PF; ++q) {
            const int s = t * PF + q;                  // runtime-uniform
            const float hi = __uint_as_float(
                __builtin_amdgcn_readlane(__float_as_uint(hr[C]), s));
            if (C != 7 || s != 63) {                   // skip nonexistent step 511
                #pragma unroll
                for (int k = 0; k < NK; ++k) {
                    const float tv = fmaf(hi, Wb[q][k].x, Wb[q][k].y);
                    const float rv = fmaxf(tv, 0.f);
                    hr[C + k] = fmaf(rv, rv, hr[C + k]);
                }
            }
            if (t + 1 < NT) {                          // refill slot q, step s+PF
                // (C==7, s+PF==63 loads row 511: in-workspace garbage, compute
                //  for that step is skipped above -> safe)
                #pragma unroll
                for (int k = 0; k < NK; ++k)
                    Wb[q][k] = base[(size_t)(s + PF) * HH + 64 * k];
            }
        }
    }
}

__global__ __launch_bounds__(256)
void scan_kernel(const float2* __restrict__ wb, float* __restrict__ h) {
    const int lane = threadIdx.x & 63;
    const int wave = threadIdx.x >> 6;
    const int row  = blockIdx.x * 4 + wave;    // 256 blocks x 4 indep waves
    float* hrow = h + (size_t)row * HH;

    float hr[8];
    #pragma unroll
    for (int k = 0; k < 8; ++k) hr[k] = hrow[lane + 64 * k];

    scan_chunk<0>(wb, hr, lane);
    scan_chunk<1>(wb, hr, lane);
    scan_chunk<2>(wb, hr, lane);
    scan_chunk<3>(wb, hr, lane);
    scan_chunk<4>(wb, hr, lane);
    scan_chunk<5>(wb, hr, lane);
    scan_chunk<6>(wb, hr, lane);
    scan_chunk<7>(wb, hr, lane);

    #pragma unroll
    for (int k = 0; k < 8; ++k) hrow[lane + 64 * k] = hr[k];
}

// ---------------------------------------------------------------------------
// workspace layout (10 MB total):
//   [0x000000, 0x200000) wb   (511*512 float2; row-511 pad read stays inside)
//   [0x200000, 0x400000) h    (1024*512 fp32)
//   [0x400000, 0x700000) Afr  (48*64*64 uint4 = 3 MB; reused for x then h)
//   [0x700000, 0x880000) Bin  (48*32*64 uint4 = 1.5 MB)
//   [0x880000, 0xA00000) Bout (1.5 MB)
// ---------------------------------------------------------------------------
extern "C" void kernel_launch(void* const* d_in, const int* in_sizes, int n_in,
                              void* d_out, int out_size, void* d_ws, size_t ws_size,
                              hipStream_t stream) {
    const float* x     = (const float*)d_in[0];
    const float* W_in  = (const float*)d_in[1];
    const float* b_in  = (const float*)d_in[2];
    const float* W_hh  = (const float*)d_in[3];
    const float* b_hh  = (const float*)d_in[4];
    const float* W_out = (const float*)d_in[5];
    const float* b_out = (const float*)d_in[6];
    float* out = (float*)d_out;

    char* ws = (char*)d_ws;
    float2* wb  = (float2*)ws;
    float*  h   = (float*)(ws + 0x200000u);
    uint4*  Afr = (uint4*)(ws + 0x400000u);
    uint4*  Bin = (uint4*)(ws + 0x700000u);
    uint4*  Bout= (uint4*)(ws + 0x880000u);

    // 1) fused prep: wb mask-interleave + x/W_in/W_out bf16 hi/lo frag-linear split
    prep_all<<<dim3(2558), dim3(256), 0, stream>>>(W_hh, b_hh, wb,
                                                   x, Afr, W_in, Bin, W_out, Bout);

    // 2) h0 = relu^2(x @ W_in + b_in)  via bf16-split MFMA
    mfma_gemm<true><<<dim3(16, 16), dim3(256), 0, stream>>>(Afr, Bin, b_in, h);

    // 3) sequential triangular scan, in-place on h (no-LDS register pipeline)
    scan_kernel<<<dim3(256), dim3(256), 0, stream>>>(wb, h);

    // 4) split post-scan h into frag-linear bf16 hi/lo
    conv_h<<<dim3(768), dim3(256), 0, stream>>>(h, Afr);

    // 5) out = h @ W_out + b_out
    mfma_gemm<false><<<dim3(16, 16), dim3(256), 0, stream>>>(Afr, Bout, b_out, out);
}